// Round 2
// baseline (1572.486 us; speedup 1.0000x reference)
//
#include <hip/hip_runtime.h>
#include <math.h>

#define N_NODES 10000
#define N_EDGES 80000
#define N_GRAPH 64
#define DD 64
#define HIDW 128
#define F_IN 14
#define EAD 4

__device__ __forceinline__ float sigmoidf_(float x){ return 1.0f/(1.0f+expf(-x)); }

// ---------- prep kernels ----------

// Hext[(h*64+i)*64+o] = h2w[h, i*64+o]   (8192 x 64)
__global__ void k_prep_hext(const float* __restrict__ h2w, float* __restrict__ Hext){
  int idx = blockIdx.x*256 + threadIdx.x;
  if (idx >= HIDW*DD*64) return;
  int k = idx >> 6, o = idx & 63;
  int h = k >> 6, i = k & 63;
  Hext[idx] = h2w[(size_t)h*4096 + i*64 + o];
}

// transpose GRU / LSTM weight matrices to k-major for coalesced reads
__global__ void k_prep_wT(const float* __restrict__ gih, const float* __restrict__ ghh,
                          const float* __restrict__ lih, const float* __restrict__ lhh,
                          float* __restrict__ WihT, float* __restrict__ WhhT,
                          float* __restrict__ IhT,  float* __restrict__ HhT){
  int idx = blockIdx.x*256 + threadIdx.x;
  if (idx < 12288){ int k=idx/192, j=idx%192; WihT[idx]=gih[j*64+k]; return; }
  idx -= 12288;
  if (idx < 12288){ int k=idx/192, j=idx%192; WhhT[idx]=ghh[j*64+k]; return; }
  idx -= 12288;
  if (idx < 32768){ int k=idx>>8, j=idx&255; IhT[idx]=lih[j*128+k]; return; }
  idx -= 32768;
  if (idx < 16384){ int k=idx>>8, j=idx&255; HhT[idx]=lhh[j*64+k]; return; }
}

// ---------- CSR build (sort edges by target) ----------

__global__ void k_count(const int* __restrict__ tgt, int* __restrict__ cnt){
  int e = blockIdx.x*256 + threadIdx.x;
  if (e < N_EDGES) atomicAdd(&cnt[tgt[e]], 1);
}

__global__ __launch_bounds__(1024) void k_scan(const int* __restrict__ cnt, int* __restrict__ offs,
                                               int* __restrict__ cursor, float* __restrict__ deg){
  __shared__ int sc[1024];
  int t = threadIdx.x;
  int base = t*10;
  int loc[10]; int tot = 0;
  #pragma unroll
  for (int j=0;j<10;++j){
    int i = base+j;
    int c = (i < N_NODES) ? cnt[i] : 0;
    loc[j] = tot; tot += c;
  }
  sc[t] = tot; __syncthreads();
  for (int st=1; st<1024; st<<=1){
    int v = (t>=st) ? sc[t-st] : 0;
    __syncthreads();
    sc[t] += v;
    __syncthreads();
  }
  int ex = sc[t] - tot;
  #pragma unroll
  for (int j=0;j<10;++j){
    int i = base+j;
    if (i < N_NODES){
      int o = ex + loc[j];
      offs[i] = o; cursor[i] = o;
      int c = cnt[i];
      deg[i] = (float)(c > 0 ? c : 1);
    }
  }
  if (t == 1023) offs[N_NODES] = sc[1023];
}

__global__ void k_sortE(const int* __restrict__ tgt, int* __restrict__ cursor, int* __restrict__ sorted){
  int e = blockIdx.x*256 + threadIdx.x;
  if (e < N_EDGES){ int p = atomicAdd(&cursor[tgt[e]], 1); sorted[p] = e; }
}

__global__ void k_graphoff(const int* __restrict__ batch, int* __restrict__ goff){
  int g = threadIdx.x;
  if (g > N_GRAPH) return;
  int lo = 0, hi = N_NODES;
  while (lo < hi){ int mid = (lo+hi)>>1; if (batch[mid] < g) lo = mid+1; else hi = mid; }
  goff[g] = lo;
}

// ---------- input layer ----------

__global__ __launch_bounds__(256) void k_lin0(const float* __restrict__ x, const float* __restrict__ w,
                                              const float* __restrict__ b, float* __restrict__ s){
  int tid = threadIdx.x;
  int g = tid >> 6, o = tid & 63;
  int n = blockIdx.x*4 + g;
  __shared__ float xL[4][F_IN];
  if (tid < 4*F_IN){
    int gg = tid / F_IN, k = tid % F_IN;
    int nn = blockIdx.x*4 + gg;
    xL[gg][k] = (nn < N_NODES) ? x[nn*F_IN + k] : 0.f;
  }
  __syncthreads();
  if (n >= N_NODES) return;
  float acc = b[o];
  #pragma unroll
  for (int k=0;k<F_IN;++k) acc += xL[g][k]*w[k*64+o];
  s[n*64+o] = fmaxf(acc, 0.f);
}

// ---------- per-iteration: chunked P build + GEMM ----------

// One target node per block. Builds P_c[t, h_local*64 + i] for h in [c0, c0+CH);
// hid recomputed on the fly from edge_attr (4 FMA per value).
template<int CH, bool WRITE_S>
__global__ __launch_bounds__(256) void k_aggpre_t(
    const float* __restrict__ s, const float* __restrict__ ea,
    const float* __restrict__ h1_w, const float* __restrict__ h1_b,
    const int* __restrict__ offs, const int* __restrict__ sorted,
    const int* __restrict__ srcA, int c0,
    float* __restrict__ P, float* __restrict__ Ssum){
  constexpr int RH = CH/4;
  int t = blockIdx.x;
  int tid = threadIdx.x;
  int i = tid & 63, hb = tid >> 6;
  __shared__ float sL[4][64];
  __shared__ float hidL[4][CH];
  __shared__ int eIdx[4], sIdx[4];
  float acc[RH];
  #pragma unroll
  for (int r=0;r<RH;++r) acc[r]=0.f;
  float sacc = 0.f;
  int e0 = offs[t], e1 = offs[t+1];
  for (int base = e0; base < e1; base += 4){
    int ecnt = min(4, e1 - base);
    __syncthreads();
    if (tid < ecnt){
      int e = sorted[base + tid];
      eIdx[tid] = e;
      sIdx[tid] = srcA[e];
    }
    __syncthreads();
    if (hb < ecnt) sL[hb][i] = s[(size_t)sIdx[hb]*64 + i];
    for (int a = tid; a < 4*CH; a += 256){
      int j = a / CH, hh = a % CH;
      if (j < ecnt){
        int e = eIdx[j];
        int h = c0 + hh;
        float v = h1_b[h];
        #pragma unroll
        for (int k=0;k<EAD;++k) v += ea[e*EAD+k]*h1_w[k*HIDW + h];
        hidL[j][hh] = fmaxf(v, 0.f);
      }
    }
    __syncthreads();
    for (int j=0;j<ecnt;++j){
      float sv = sL[j][i];
      #pragma unroll
      for (int r=0;r<RH;++r) acc[r] += hidL[j][hb*RH + r]*sv;
      if (WRITE_S && hb==0) sacc += sv;
    }
  }
  float* row = P + (size_t)t*(CH*64);
  #pragma unroll
  for (int r=0;r<RH;++r) row[(hb*RH + r)*64 + i] = acc[r];
  if (WRITE_S && hb==0) Ssum[(size_t)t*64 + i] = sacc;
}

// C[10000,64] (+)= A[10000,KC] @ B[KC,64]; 16 rows per block, full-K, no atomics
__global__ __launch_bounds__(256) void k_gemm_acc(const float* __restrict__ A, const float* __restrict__ B,
                                                  float* __restrict__ C, int KC, int first){
  __shared__ __align__(16) float As[16][68];
  __shared__ __align__(16) float Bs[64][64];
  int r0 = blockIdx.x * 16;
  int tid = threadIdx.x;
  int tx = tid & 15, ty = tid >> 4;
  float acc[4] = {0,0,0,0};
  for (int k0 = 0; k0 < KC; k0 += 64){
    {
      int rr = ty, kk4 = tx*4;
      int r = r0 + rr;
      float4 v = make_float4(0,0,0,0);
      if (r < N_NODES) v = *(const float4*)(A + (size_t)r*KC + k0 + kk4);
      *(float4*)&As[rr][kk4] = v;
    }
    #pragma unroll
    for (int p=0;p<4;++p){
      int idx = tid + p*256;
      int kk = idx >> 4, oo4 = (idx & 15)*4;
      *(float4*)&Bs[kk][oo4] = *(const float4*)(B + (size_t)(k0+kk)*64 + oo4);
    }
    __syncthreads();
    #pragma unroll
    for (int kk=0; kk<64; ++kk){
      float a0 = As[ty][kk];
      float4 b = *(const float4*)&Bs[kk][tx*4];
      acc[0] += a0*b.x; acc[1] += a0*b.y; acc[2] += a0*b.z; acc[3] += a0*b.w;
    }
    __syncthreads();
  }
  int r = r0 + ty;
  if (r < N_NODES){
    float4* cp = (float4*)(C + (size_t)r*64 + tx*4);
    float4 v = make_float4(acc[0],acc[1],acc[2],acc[3]);
    if (!first){ float4 o4 = *cp; v.x+=o4.x; v.y+=o4.y; v.z+=o4.z; v.w+=o4.w; }
    *cp = v;
  }
}

// fallback: fused P-in-LDS + in-block GEMM vs L2-resident Hext (no big workspace)
__global__ __launch_bounds__(256) void k_msg_fused(
    const float* __restrict__ s, const float* __restrict__ ea,
    const float* __restrict__ h1_w, const float* __restrict__ h1_b,
    const int* __restrict__ offs, const int* __restrict__ sorted,
    const int* __restrict__ srcA, const float* __restrict__ Hext,
    float* __restrict__ aggsum, float* __restrict__ Ssum){
  int t = blockIdx.x;
  int tid = threadIdx.x;
  int i = tid & 63, hb = tid >> 6;
  __shared__ float Pl[HIDW*64];
  __shared__ float sL[4][64];
  __shared__ float hidL[4][HIDW];
  __shared__ int eIdx[4], sIdx[4];
  __shared__ float sS[64];
  __shared__ float red[4][64];
  float acc[32];
  #pragma unroll
  for (int r=0;r<32;++r) acc[r]=0.f;
  float sacc = 0.f;
  int e0 = offs[t], e1 = offs[t+1];
  for (int base = e0; base < e1; base += 4){
    int ecnt = min(4, e1 - base);
    __syncthreads();
    if (tid < ecnt){
      int e = sorted[base + tid];
      eIdx[tid] = e;
      sIdx[tid] = srcA[e];
    }
    __syncthreads();
    if (hb < ecnt) sL[hb][i] = s[(size_t)sIdx[hb]*64 + i];
    for (int a = tid; a < 4*HIDW; a += 256){
      int j = a >> 7, hh = a & 127;
      if (j < ecnt){
        int e = eIdx[j];
        float v = h1_b[hh];
        #pragma unroll
        for (int k=0;k<EAD;++k) v += ea[e*EAD+k]*h1_w[k*HIDW + hh];
        hidL[j][hh] = fmaxf(v, 0.f);
      }
    }
    __syncthreads();
    for (int j=0;j<ecnt;++j){
      float sv = sL[j][i];
      #pragma unroll
      for (int r=0;r<32;++r) acc[r] += hidL[j][hb*32 + r]*sv;
      if (hb==0) sacc += sv;
    }
  }
  __syncthreads();
  #pragma unroll
  for (int r=0;r<32;++r) Pl[(hb*32 + r)*64 + i] = acc[r];
  if (hb==0) sS[i] = sacc;
  __syncthreads();
  float a2 = 0.f;
  for (int k = hb*2048; k < hb*2048 + 2048; ++k)
    a2 += Pl[k]*Hext[(size_t)k*64 + i];
  red[hb][i] = a2;
  __syncthreads();
  if (hb==0){
    aggsum[(size_t)t*64 + i] = red[0][i]+red[1][i]+red[2][i]+red[3][i];
    Ssum[(size_t)t*64 + i] = sS[i];
  }
}

// fused: mean-deg, bias term (Ssum@h2b), conv-root, relu, GRU cell (in-place on s)
__global__ __launch_bounds__(256) void k_node_update(const float* __restrict__ aggsum,
    const float* __restrict__ Ssum, const float* __restrict__ h2b,
    const float* __restrict__ deg, float* __restrict__ s,
    const float* __restrict__ conv_root, const float* __restrict__ conv_bias,
    const float* __restrict__ WihT, const float* __restrict__ WhhT,
    const float* __restrict__ bih, const float* __restrict__ bhh){
  int tid = threadIdx.x;
  int g = tid >> 6, o = tid & 63;
  int n = blockIdx.x*4 + g;
  __shared__ float hS[4][DD];
  __shared__ float mS[4][DD];
  __shared__ float ssS[4][DD];
  bool valid = n < N_NODES;
  float hold = valid ? s[(size_t)n*DD + o] : 0.f;
  hS[g][o] = hold;
  ssS[g][o] = valid ? Ssum[(size_t)n*DD + o] : 0.f;
  __syncthreads();
  float a = valid ? aggsum[(size_t)n*DD + o] : 0.f;
  #pragma unroll 8
  for (int k=0;k<DD;++k) a += ssS[g][k]*h2b[k*64+o];
  float dinv = valid ? 1.0f/deg[n] : 0.f;
  float acc = a*dinv + conv_bias[o];
  #pragma unroll 8
  for (int k=0;k<DD;++k) acc += hS[g][k]*conv_root[k*64+o];
  float m = fmaxf(acc, 0.f);
  mS[g][o] = m;
  __syncthreads();
  float gi0 = bih[o], gi1 = bih[64+o], gi2 = bih[128+o];
  float gh0 = bhh[o], gh1 = bhh[64+o], gh2 = bhh[128+o];
  for (int k=0;k<DD;++k){
    float mk = mS[g][k], hk = hS[g][k];
    gi0 += mk*WihT[k*192 + o];      gh0 += hk*WhhT[k*192 + o];
    gi1 += mk*WihT[k*192 + 64 + o]; gh1 += hk*WhhT[k*192 + 64 + o];
    gi2 += mk*WihT[k*192 + 128+ o]; gh2 += hk*WhhT[k*192 + 128+ o];
  }
  float r = sigmoidf_(gi0+gh0);
  float z = sigmoidf_(gi1+gh1);
  float nn = tanhf(gi2 + r*gh2);
  float hnew = (1.f - z)*nn + z*hold;
  if (valid) s[(size_t)n*DD + o] = hnew;
}

// ---------- Set2Set ----------

__global__ __launch_bounds__(256) void k_lstm(const float* __restrict__ qstar,
    float* __restrict__ hs, float* __restrict__ cs,
    const float* __restrict__ IhT, const float* __restrict__ HhT,
    const float* __restrict__ bih, const float* __restrict__ bhh){
  int g = blockIdx.x;
  int tid = threadIdx.x;
  __shared__ float qL[2*DD];
  __shared__ float hL[DD];
  __shared__ float gate[256];
  if (tid < 2*DD) qL[tid] = qstar[g*2*DD + tid];
  else if (tid < 3*DD) hL[tid - 2*DD] = hs[g*DD + (tid - 2*DD)];
  __syncthreads();
  float acc = bih[tid] + bhh[tid];
  #pragma unroll 8
  for (int k=0;k<2*DD;++k) acc += qL[k]*IhT[k*256 + tid];
  #pragma unroll 8
  for (int k=0;k<DD;++k)   acc += hL[k]*HhT[k*256 + tid];
  gate[tid] = acc;
  __syncthreads();
  if (tid < DD){
    float i = sigmoidf_(gate[tid]);
    float f = sigmoidf_(gate[64+tid]);
    float gg = tanhf(gate[128+tid]);
    float o = sigmoidf_(gate[192+tid]);
    float c = f*cs[g*DD+tid] + i*gg;
    float h = o*tanhf(c);
    cs[g*DD+tid] = c;
    hs[g*DD+tid] = h;
  }
}

__global__ __launch_bounds__(256) void k_attn(const float* __restrict__ sND, const float* __restrict__ hs,
    const int* __restrict__ goff, float* __restrict__ qstar){
  int g = blockIdx.x;
  int tid = threadIdx.x;
  int lane = tid & 63, w = tid >> 6;
  int n0 = goff[g], n1 = goff[g+1];
  __shared__ float hL[DD];
  __shared__ float red[4];
  __shared__ float red2[4][DD];
  if (tid < DD) hL[tid] = hs[g*DD + tid];
  __syncthreads();
  float wmax = -INFINITY;
  for (int n = n0 + w; n < n1; n += 4){
    float p = sND[(size_t)n*DD + lane] * hL[lane];
    #pragma unroll
    for (int s2=32; s2>0; s2>>=1) p += __shfl_xor(p, s2, 64);
    wmax = fmaxf(wmax, p);
  }
  if (lane == 0) red[w] = wmax;
  __syncthreads();
  float m = fmaxf(fmaxf(red[0], red[1]), fmaxf(red[2], red[3]));
  __syncthreads();
  float wsum = 0.f;
  float racc = 0.f;
  for (int n = n0 + w; n < n1; n += 4){
    float outv = sND[(size_t)n*DD + lane];
    float p = outv * hL[lane];
    #pragma unroll
    for (int s2=32; s2>0; s2>>=1) p += __shfl_xor(p, s2, 64);
    float ex = expf(p - m);
    wsum += ex;
    racc += ex * outv;
  }
  if (lane == 0) red[w] = wsum;
  red2[w][lane] = racc;
  __syncthreads();
  if (w == 0){
    float stot = red[0]+red[1]+red[2]+red[3];
    float rsum = red2[0][lane]+red2[1][lane]+red2[2][lane]+red2[3][lane];
    float r = (stot > 0.f) ? rsum/stot : 0.f;
    qstar[g*2*DD + lane]      = hL[lane];
    qstar[g*2*DD + DD + lane] = r;
  }
}

__global__ __launch_bounds__(256) void k_final(const float* __restrict__ qstar,
    const float* __restrict__ lin1_w, const float* __restrict__ lin1_b,
    const float* __restrict__ lin2_w, const float* __restrict__ lin2_b,
    float* __restrict__ out){
  __shared__ float red[256];
  int tid = threadIdx.x;
  int g = tid >> 2, part = tid & 3;
  float acc = 0.f;
  for (int d = part*16; d < part*16+16; ++d){
    float z = lin1_b[d];
    #pragma unroll 8
    for (int k=0;k<2*DD;++k) z += qstar[g*2*DD+k]*lin1_w[k*64+d];
    z = fmaxf(z, 0.f);
    acc += z * lin2_w[d];
  }
  red[tid] = acc;
  __syncthreads();
  if (part == 0) out[g] = red[tid]+red[tid+1]+red[tid+2]+red[tid+3] + lin2_b[0];
}

// ---------- launch ----------

static inline size_t alignup(size_t x){ return (x + 255) & ~(size_t)255; }

extern "C" void kernel_launch(void* const* d_in, const int* in_sizes, int n_in,
                              void* d_out, int out_size, void* d_ws, size_t ws_size,
                              hipStream_t stream){
  const float* x      = (const float*)d_in[0];
  const int*   ei     = (const int*)  d_in[1];
  const float* ea     = (const float*)d_in[2];
  const int*   batch  = (const int*)  d_in[3];
  const float* lin0_w = (const float*)d_in[5];
  const float* lin0_b = (const float*)d_in[6];
  const float* h1_w   = (const float*)d_in[7];
  const float* h1_b   = (const float*)d_in[8];
  const float* h2_w   = (const float*)d_in[9];
  const float* h2_b   = (const float*)d_in[10];
  const float* conv_root = (const float*)d_in[11];
  const float* conv_bias = (const float*)d_in[12];
  const float* gru_w_ih  = (const float*)d_in[13];
  const float* gru_w_hh  = (const float*)d_in[14];
  const float* gru_b_ih  = (const float*)d_in[15];
  const float* gru_b_hh  = (const float*)d_in[16];
  const float* lstm_w_ih = (const float*)d_in[17];
  const float* lstm_w_hh = (const float*)d_in[18];
  const float* lstm_b_ih = (const float*)d_in[19];
  const float* lstm_b_hh = (const float*)d_in[20];
  const float* lin1_w = (const float*)d_in[21];
  const float* lin1_b = (const float*)d_in[22];
  const float* lin2_w = (const float*)d_in[23];
  const float* lin2_b = (const float*)d_in[24];
  (void)in_sizes; (void)n_in; (void)out_size;

  const int* srcA = ei;
  const int* tgtA = ei + N_EDGES;

  // ---- fixed workspace layout (~10.8 MB) ----
  char* p = (char*)d_ws;
  size_t off = 0;
  auto take = [&](size_t bytes)->char*{ char* q = p + off; off = alignup(off + bytes); return q; };
  float* Hext    = (float*)take((size_t)HIDW*DD*64*4);   // 2.10 MB
  float* sbuf    = (float*)take((size_t)N_NODES*DD*4);   // 2.56 MB
  float* aggsum  = (float*)take((size_t)N_NODES*DD*4);   // 2.56 MB
  float* Ssum    = (float*)take((size_t)N_NODES*DD*4);   // 2.56 MB
  float* WihT    = (float*)take(12288*4);
  float* WhhT    = (float*)take(12288*4);
  float* IhT     = (float*)take(32768*4);
  float* HhT     = (float*)take(16384*4);
  float* deg     = (float*)take(N_NODES*4);
  int*   cnt     = (int*)  take(N_NODES*4);
  int*   offs    = (int*)  take((N_NODES+1)*4);
  int*   cursor  = (int*)  take(N_NODES*4);
  int*   sorted  = (int*)  take(N_EDGES*4);
  int*   goff    = (int*)  take(65*4);
  float* hs      = (float*)take((size_t)N_GRAPH*(DD+DD+2*DD)*4);
  float* cs      = hs + N_GRAPH*DD;
  float* qstar   = cs + N_GRAPH*DD;
  size_t fixed_bytes = off;

  // ---- adaptive P-chunk selection ----
  int CH = 0;
  const int cands[6] = {128, 64, 32, 16, 8, 4};
  for (int ci = 0; ci < 6; ++ci){
    size_t need = fixed_bytes + (size_t)N_NODES * cands[ci] * 64 * 4;
    if (need <= ws_size){ CH = cands[ci]; break; }
  }
  float* Pbuf = (CH > 0) ? (float*)take((size_t)N_NODES*CH*64*4) : nullptr;

  hipMemsetAsync(cnt, 0, N_NODES*4, stream);
  hipMemsetAsync(hs, 0, (size_t)N_GRAPH*(DD+DD+2*DD)*4, stream);

  k_prep_hext<<<HIDW*DD*64/256, 256, 0, stream>>>(h2_w, Hext);
  k_prep_wT<<<(12288*2+32768+16384)/256, 256, 0, stream>>>(gru_w_ih, gru_w_hh, lstm_w_ih, lstm_w_hh,
                                                           WihT, WhhT, IhT, HhT);
  k_count<<<(N_EDGES+255)/256, 256, 0, stream>>>(tgtA, cnt);
  k_scan<<<1, 1024, 0, stream>>>(cnt, offs, cursor, deg);
  k_sortE<<<(N_EDGES+255)/256, 256, 0, stream>>>(tgtA, cursor, sorted);
  k_graphoff<<<1, 128, 0, stream>>>(batch, goff);
  k_lin0<<<N_NODES/4, 256, 0, stream>>>(x, lin0_w, lin0_b, sbuf);

  auto launch_agg = [&](int c0, bool writeS){
    dim3 g(N_NODES);
    if (writeS){
      switch (CH){
        case 128: k_aggpre_t<128,true><<<g,256,0,stream>>>(sbuf,ea,h1_w,h1_b,offs,sorted,srcA,c0,Pbuf,Ssum); break;
        case  64: k_aggpre_t< 64,true><<<g,256,0,stream>>>(sbuf,ea,h1_w,h1_b,offs,sorted,srcA,c0,Pbuf,Ssum); break;
        case  32: k_aggpre_t< 32,true><<<g,256,0,stream>>>(sbuf,ea,h1_w,h1_b,offs,sorted,srcA,c0,Pbuf,Ssum); break;
        case  16: k_aggpre_t< 16,true><<<g,256,0,stream>>>(sbuf,ea,h1_w,h1_b,offs,sorted,srcA,c0,Pbuf,Ssum); break;
        case   8: k_aggpre_t<  8,true><<<g,256,0,stream>>>(sbuf,ea,h1_w,h1_b,offs,sorted,srcA,c0,Pbuf,Ssum); break;
        default : k_aggpre_t<  4,true><<<g,256,0,stream>>>(sbuf,ea,h1_w,h1_b,offs,sorted,srcA,c0,Pbuf,Ssum); break;
      }
    } else {
      switch (CH){
        case 128: k_aggpre_t<128,false><<<g,256,0,stream>>>(sbuf,ea,h1_w,h1_b,offs,sorted,srcA,c0,Pbuf,Ssum); break;
        case  64: k_aggpre_t< 64,false><<<g,256,0,stream>>>(sbuf,ea,h1_w,h1_b,offs,sorted,srcA,c0,Pbuf,Ssum); break;
        case  32: k_aggpre_t< 32,false><<<g,256,0,stream>>>(sbuf,ea,h1_w,h1_b,offs,sorted,srcA,c0,Pbuf,Ssum); break;
        case  16: k_aggpre_t< 16,false><<<g,256,0,stream>>>(sbuf,ea,h1_w,h1_b,offs,sorted,srcA,c0,Pbuf,Ssum); break;
        case   8: k_aggpre_t<  8,false><<<g,256,0,stream>>>(sbuf,ea,h1_w,h1_b,offs,sorted,srcA,c0,Pbuf,Ssum); break;
        default : k_aggpre_t<  4,false><<<g,256,0,stream>>>(sbuf,ea,h1_w,h1_b,offs,sorted,srcA,c0,Pbuf,Ssum); break;
      }
    }
  };

  for (int it = 0; it < 3; ++it){
    if (CH > 0){
      int nch = HIDW / CH;
      for (int c = 0; c < nch; ++c){
        launch_agg(c*CH, c == 0);
        k_gemm_acc<<<(N_NODES+15)/16, 256, 0, stream>>>(Pbuf, Hext + (size_t)c*CH*64*64,
                                                        aggsum, CH*64, c == 0);
      }
    } else {
      k_msg_fused<<<N_NODES, 256, 0, stream>>>(sbuf, ea, h1_w, h1_b, offs, sorted, srcA,
                                               Hext, aggsum, Ssum);
    }
    k_node_update<<<N_NODES/4, 256, 0, stream>>>(aggsum, Ssum, h2_b, deg, sbuf, conv_root, conv_bias,
                                                 WihT, WhhT, gru_b_ih, gru_b_hh);
  }

  for (int st = 0; st < 3; ++st){
    k_lstm<<<N_GRAPH, 256, 0, stream>>>(qstar, hs, cs, IhT, HhT, lstm_b_ih, lstm_b_hh);
    k_attn<<<N_GRAPH, 256, 0, stream>>>(sbuf, hs, goff, qstar);
  }
  k_final<<<1, 256, 0, stream>>>(qstar, lin1_w, lin1_b, lin2_w, lin2_b, (float*)d_out);
}

// Round 3
// 1055.047 us; speedup vs baseline: 1.4904x; 1.4904x over previous
//
#include <hip/hip_runtime.h>
#include <math.h>

#define N_NODES 10000
#define N_EDGES 80000
#define N_GRAPH 64
#define DD 64
#define HIDW 128
#define F_IN 14
#define EAD 4

typedef _Float16 f16x8 __attribute__((ext_vector_type(8)));
typedef float f32x4 __attribute__((ext_vector_type(4)));

__device__ __forceinline__ float sigmoidf_(float x){ return 1.0f/(1.0f+expf(-x)); }

// ---------- prep kernels ----------

// Pack Hext (h2_w rearranged) into fp16 MFMA B-fragment order:
// Bp[((st*4+cg)*64+lane)*8+j] = h2w[h, i*64+o], k=st*32+(lane>>4)*8+j, o=cg*16+(lane&15), h=k>>6, i=k&63
__global__ void k_prep_bpack(const float* __restrict__ h2w, _Float16* __restrict__ Bp){
  int idx = blockIdx.x*256 + threadIdx.x;
  if (idx >= (HIDW*DD/32)*4*64*8) return;
  int j = idx & 7, l = (idx >> 3) & 63, cg = (idx >> 9) & 3, st = idx >> 11;
  int k = st*32 + ((l >> 4) << 3) + j;
  int o = cg*16 + (l & 15);
  int h = k >> 6, i = k & 63;
  Bp[idx] = (_Float16)h2w[(size_t)h*4096 + i*64 + o];
}

// transpose GRU / LSTM weight matrices to k-major for coalesced reads
__global__ void k_prep_wT(const float* __restrict__ gih, const float* __restrict__ ghh,
                          const float* __restrict__ lih, const float* __restrict__ lhh,
                          float* __restrict__ WihT, float* __restrict__ WhhT,
                          float* __restrict__ IhT,  float* __restrict__ HhT){
  int idx = blockIdx.x*256 + threadIdx.x;
  if (idx < 12288){ int k=idx/192, j=idx%192; WihT[idx]=gih[j*64+k]; return; }
  idx -= 12288;
  if (idx < 12288){ int k=idx/192, j=idx%192; WhhT[idx]=ghh[j*64+k]; return; }
  idx -= 12288;
  if (idx < 32768){ int k=idx>>8, j=idx&255; IhT[idx]=lih[j*128+k]; return; }
  idx -= 32768;
  if (idx < 16384){ int k=idx>>8, j=idx&255; HhT[idx]=lhh[j*64+k]; return; }
}

// ---------- CSR build (sort edges by target) ----------

__global__ void k_count(const int* __restrict__ tgt, int* __restrict__ cnt){
  int e = blockIdx.x*256 + threadIdx.x;
  if (e < N_EDGES) atomicAdd(&cnt[tgt[e]], 1);
}

__global__ __launch_bounds__(1024) void k_scan(const int* __restrict__ cnt, int* __restrict__ offs,
                                               int* __restrict__ cursor, float* __restrict__ deg){
  __shared__ int sc[1024];
  int t = threadIdx.x;
  int base = t*10;
  int loc[10]; int tot = 0;
  #pragma unroll
  for (int j=0;j<10;++j){
    int i = base+j;
    int c = (i < N_NODES) ? cnt[i] : 0;
    loc[j] = tot; tot += c;
  }
  sc[t] = tot; __syncthreads();
  for (int st=1; st<1024; st<<=1){
    int v = (t>=st) ? sc[t-st] : 0;
    __syncthreads();
    sc[t] += v;
    __syncthreads();
  }
  int ex = sc[t] - tot;
  #pragma unroll
  for (int j=0;j<10;++j){
    int i = base+j;
    if (i < N_NODES){
      int o = ex + loc[j];
      offs[i] = o; cursor[i] = o;
      int c = cnt[i];
      deg[i] = (float)(c > 0 ? c : 1);
    }
  }
  if (t == 1023) offs[N_NODES] = sc[1023];
}

__global__ void k_sortE(const int* __restrict__ tgt, int* __restrict__ cursor, int* __restrict__ sorted){
  int e = blockIdx.x*256 + threadIdx.x;
  if (e < N_EDGES){ int p = atomicAdd(&cursor[tgt[e]], 1); sorted[p] = e; }
}

__global__ void k_graphoff(const int* __restrict__ batch, int* __restrict__ goff){
  int g = threadIdx.x;
  if (g > N_GRAPH) return;
  int lo = 0, hi = N_NODES;
  while (lo < hi){ int mid = (lo+hi)>>1; if (batch[mid] < g) lo = mid+1; else hi = mid; }
  goff[g] = lo;
}

// ---------- input layer ----------

__global__ __launch_bounds__(256) void k_lin0(const float* __restrict__ x, const float* __restrict__ w,
                                              const float* __restrict__ b, float* __restrict__ s){
  int tid = threadIdx.x;
  int g = tid >> 6, o = tid & 63;
  int n = blockIdx.x*4 + g;
  __shared__ float xL[4][F_IN];
  if (tid < 4*F_IN){
    int gg = tid / F_IN, k = tid % F_IN;
    int nn = blockIdx.x*4 + gg;
    xL[gg][k] = (nn < N_NODES) ? x[nn*F_IN + k] : 0.f;
  }
  __syncthreads();
  if (n >= N_NODES) return;
  float acc = b[o];
  #pragma unroll
  for (int k=0;k<F_IN;++k) acc += xL[g][k]*w[k*64+o];
  s[n*64+o] = fmaxf(acc, 0.f);
}

// ---------- per-iteration: P build (fp16 out) + MFMA GEMM ----------

template<int CH, bool WRITE_S>
__global__ __launch_bounds__(256) void k_aggpre_t(
    const float* __restrict__ s, const float* __restrict__ ea,
    const float* __restrict__ h1_w, const float* __restrict__ h1_b,
    const int* __restrict__ offs, const int* __restrict__ sorted,
    const int* __restrict__ srcA, int c0,
    _Float16* __restrict__ P, float* __restrict__ Ssum){
  constexpr int RH = CH/4;
  int t = blockIdx.x;
  int tid = threadIdx.x;
  int i = tid & 63, hb = tid >> 6;
  __shared__ float sL[4][64];
  __shared__ float hidL[4][CH];
  __shared__ int eIdx[4], sIdx[4];
  float acc[RH];
  #pragma unroll
  for (int r=0;r<RH;++r) acc[r]=0.f;
  float sacc = 0.f;
  int e0 = offs[t], e1 = offs[t+1];
  for (int base = e0; base < e1; base += 4){
    int ecnt = min(4, e1 - base);
    __syncthreads();
    if (tid < ecnt){
      int e = sorted[base + tid];
      eIdx[tid] = e;
      sIdx[tid] = srcA[e];
    }
    __syncthreads();
    if (hb < ecnt) sL[hb][i] = s[(size_t)sIdx[hb]*64 + i];
    for (int a = tid; a < 4*CH; a += 256){
      int j = a / CH, hh = a % CH;
      if (j < ecnt){
        int e = eIdx[j];
        int h = c0 + hh;
        float v = h1_b[h];
        #pragma unroll
        for (int k=0;k<EAD;++k) v += ea[e*EAD+k]*h1_w[k*HIDW + h];
        hidL[j][hh] = fmaxf(v, 0.f);
      }
    }
    __syncthreads();
    for (int j=0;j<ecnt;++j){
      float sv = sL[j][i];
      #pragma unroll
      for (int r=0;r<RH;++r) acc[r] += hidL[j][hb*RH + r]*sv;
      if (WRITE_S && hb==0) sacc += sv;
    }
  }
  _Float16* row = P + (size_t)t*(CH*64);
  #pragma unroll
  for (int r=0;r<RH;++r) row[(hb*RH + r)*64 + i] = (_Float16)acc[r];
  if (WRITE_S && hb==0) Ssum[(size_t)t*64 + i] = sacc;
}

// C[10000,64] (+)= A[10000,K] @ B[K,64] via mfma_f32_16x16x32_f16.
// A fp16 row-major; Bp pre-packed fragment order; 2 waves/block, 16 rows each.
__global__ __launch_bounds__(128) void k_gemm_mfma(const _Float16* __restrict__ A,
    const _Float16* __restrict__ Bp, float* __restrict__ C, int K, int first){
  int wave = threadIdx.x >> 6, lane = threadIdx.x & 63;
  int rowA = blockIdx.x*32 + wave*16 + (lane & 15);
  int kb = lane >> 4;
  bool rv = rowA < N_NODES;
  const _Float16* arow = A + (size_t)rowA*K + kb*8;
  const f16x8* bp = (const f16x8*)Bp;
  f32x4 acc0 = 0.f, acc1 = 0.f, acc2 = 0.f, acc3 = 0.f;
  int nst = K >> 5;
  #pragma unroll 2
  for (int st = 0; st < nst; ++st){
    f16x8 af = (f16x8)(_Float16)0;
    if (rv) af = *(const f16x8*)(arow + (size_t)st*32);
    size_t bbase = (size_t)(st*4)*64 + lane;
    f16x8 b0 = bp[bbase];
    f16x8 b1 = bp[bbase + 64];
    f16x8 b2 = bp[bbase + 128];
    f16x8 b3 = bp[bbase + 192];
    acc0 = __builtin_amdgcn_mfma_f32_16x16x32_f16(af, b0, acc0, 0, 0, 0);
    acc1 = __builtin_amdgcn_mfma_f32_16x16x32_f16(af, b1, acc1, 0, 0, 0);
    acc2 = __builtin_amdgcn_mfma_f32_16x16x32_f16(af, b2, acc2, 0, 0, 0);
    acc3 = __builtin_amdgcn_mfma_f32_16x16x32_f16(af, b3, acc3, 0, 0, 0);
  }
  int crow0 = blockIdx.x*32 + wave*16 + (lane >> 4)*4;
  int ccol = lane & 15;
  #pragma unroll
  for (int r=0;r<4;++r){
    int cr = crow0 + r;
    if (cr < N_NODES){
      float* cp = C + (size_t)cr*64 + ccol;
      if (first){
        cp[0]  = acc0[r]; cp[16] = acc1[r]; cp[32] = acc2[r]; cp[48] = acc3[r];
      } else {
        cp[0]  += acc0[r]; cp[16] += acc1[r]; cp[32] += acc2[r]; cp[48] += acc3[r];
      }
    }
  }
}

// fused: mean-deg, bias term (Ssum@h2b), conv-root, relu, GRU cell (in-place on s)
__global__ __launch_bounds__(256) void k_node_update(const float* __restrict__ aggsum,
    const float* __restrict__ Ssum, const float* __restrict__ h2b,
    const float* __restrict__ deg, float* __restrict__ s,
    const float* __restrict__ conv_root, const float* __restrict__ conv_bias,
    const float* __restrict__ WihT, const float* __restrict__ WhhT,
    const float* __restrict__ bih, const float* __restrict__ bhh){
  int tid = threadIdx.x;
  int g = tid >> 6, o = tid & 63;
  int n = blockIdx.x*4 + g;
  __shared__ float hS[4][DD];
  __shared__ float mS[4][DD];
  __shared__ float ssS[4][DD];
  bool valid = n < N_NODES;
  float hold = valid ? s[(size_t)n*DD + o] : 0.f;
  hS[g][o] = hold;
  ssS[g][o] = valid ? Ssum[(size_t)n*DD + o] : 0.f;
  __syncthreads();
  float a = valid ? aggsum[(size_t)n*DD + o] : 0.f;
  #pragma unroll 8
  for (int k=0;k<DD;++k) a += ssS[g][k]*h2b[k*64+o];
  float dinv = valid ? 1.0f/deg[n] : 0.f;
  float acc = a*dinv + conv_bias[o];
  #pragma unroll 8
  for (int k=0;k<DD;++k) acc += hS[g][k]*conv_root[k*64+o];
  float m = fmaxf(acc, 0.f);
  mS[g][o] = m;
  __syncthreads();
  float gi0 = bih[o], gi1 = bih[64+o], gi2 = bih[128+o];
  float gh0 = bhh[o], gh1 = bhh[64+o], gh2 = bhh[128+o];
  for (int k=0;k<DD;++k){
    float mk = mS[g][k], hk = hS[g][k];
    gi0 += mk*WihT[k*192 + o];      gh0 += hk*WhhT[k*192 + o];
    gi1 += mk*WihT[k*192 + 64 + o]; gh1 += hk*WhhT[k*192 + 64 + o];
    gi2 += mk*WihT[k*192 + 128+ o]; gh2 += hk*WhhT[k*192 + 128+ o];
  }
  float r = sigmoidf_(gi0+gh0);
  float z = sigmoidf_(gi1+gh1);
  float nn = tanhf(gi2 + r*gh2);
  float hnew = (1.f - z)*nn + z*hold;
  if (valid) s[(size_t)n*DD + o] = hnew;
}

// ---------- Set2Set: all 3 steps fused, one block per graph ----------

__global__ __launch_bounds__(256) void k_set2set(const float* __restrict__ sND,
    const int* __restrict__ goff,
    const float* __restrict__ IhT, const float* __restrict__ HhT,
    const float* __restrict__ bih, const float* __restrict__ bhh,
    float* __restrict__ qstarOut){
  int g = blockIdx.x;
  int tid = threadIdx.x;
  int lane = tid & 63, w = tid >> 6;
  __shared__ float qL[2*DD];
  __shared__ float hL[DD];
  __shared__ float cL[DD];
  __shared__ float gate[256];
  __shared__ float red[4];
  __shared__ float red2[4][DD];
  if (tid < 2*DD) qL[tid] = 0.f;
  if (tid < DD){ hL[tid] = 0.f; cL[tid] = 0.f; }
  __syncthreads();
  int n0 = goff[g], n1 = goff[g+1];
  for (int st = 0; st < 3; ++st){
    // LSTM cell: gate j = tid
    float acc = bih[tid] + bhh[tid];
    #pragma unroll 8
    for (int k=0;k<2*DD;++k) acc += qL[k]*IhT[k*256 + tid];
    #pragma unroll 8
    for (int k=0;k<DD;++k)   acc += hL[k]*HhT[k*256 + tid];
    gate[tid] = acc;
    __syncthreads();
    if (tid < DD){
      float i = sigmoidf_(gate[tid]);
      float f = sigmoidf_(gate[64+tid]);
      float gg = tanhf(gate[128+tid]);
      float o = sigmoidf_(gate[192+tid]);
      float c = f*cL[tid] + i*gg;
      float h = o*tanhf(c);
      cL[tid] = c; hL[tid] = h;
    }
    __syncthreads();
    // attention pass 1: per-graph max of e_n
    float wmax = -INFINITY;
    for (int n = n0 + w; n < n1; n += 4){
      float p = sND[(size_t)n*DD + lane] * hL[lane];
      #pragma unroll
      for (int s2=32; s2>0; s2>>=1) p += __shfl_xor(p, s2, 64);
      wmax = fmaxf(wmax, p);
    }
    if (lane == 0) red[w] = wmax;
    __syncthreads();
    float m = fmaxf(fmaxf(red[0], red[1]), fmaxf(red[2], red[3]));
    __syncthreads();
    // pass 2: exp-sum + weighted node sum
    float wsum = 0.f, racc = 0.f;
    for (int n = n0 + w; n < n1; n += 4){
      float outv = sND[(size_t)n*DD + lane];
      float p = outv * hL[lane];
      #pragma unroll
      for (int s2=32; s2>0; s2>>=1) p += __shfl_xor(p, s2, 64);
      float ex = expf(p - m);
      wsum += ex;
      racc += ex * outv;
    }
    if (lane == 0) red[w] = wsum;
    red2[w][lane] = racc;
    __syncthreads();
    if (tid < DD){
      float stot = red[0]+red[1]+red[2]+red[3];
      float rsum = red2[0][tid]+red2[1][tid]+red2[2][tid]+red2[3][tid];
      float r = (stot > 0.f) ? rsum/stot : 0.f;
      qL[tid] = hL[tid];
      qL[DD + tid] = r;
    }
    __syncthreads();
  }
  if (tid < 2*DD) qstarOut[g*2*DD + tid] = qL[tid];
}

__global__ __launch_bounds__(256) void k_final(const float* __restrict__ qstar,
    const float* __restrict__ lin1_w, const float* __restrict__ lin1_b,
    const float* __restrict__ lin2_w, const float* __restrict__ lin2_b,
    float* __restrict__ out){
  __shared__ float red[256];
  int tid = threadIdx.x;
  int g = tid >> 2, part = tid & 3;
  float acc = 0.f;
  for (int d = part*16; d < part*16+16; ++d){
    float z = lin1_b[d];
    #pragma unroll 8
    for (int k=0;k<2*DD;++k) z += qstar[g*2*DD+k]*lin1_w[k*64+d];
    z = fmaxf(z, 0.f);
    acc += z * lin2_w[d];
  }
  red[tid] = acc;
  __syncthreads();
  if (part == 0) out[g] = red[tid]+red[tid+1]+red[tid+2]+red[tid+3] + lin2_b[0];
}

// ---------- launch ----------

static inline size_t alignup(size_t x){ return (x + 255) & ~(size_t)255; }

extern "C" void kernel_launch(void* const* d_in, const int* in_sizes, int n_in,
                              void* d_out, int out_size, void* d_ws, size_t ws_size,
                              hipStream_t stream){
  const float* x      = (const float*)d_in[0];
  const int*   ei     = (const int*)  d_in[1];
  const float* ea     = (const float*)d_in[2];
  const int*   batch  = (const int*)  d_in[3];
  const float* lin0_w = (const float*)d_in[5];
  const float* lin0_b = (const float*)d_in[6];
  const float* h1_w   = (const float*)d_in[7];
  const float* h1_b   = (const float*)d_in[8];
  const float* h2_w   = (const float*)d_in[9];
  const float* h2_b   = (const float*)d_in[10];
  const float* conv_root = (const float*)d_in[11];
  const float* conv_bias = (const float*)d_in[12];
  const float* gru_w_ih  = (const float*)d_in[13];
  const float* gru_w_hh  = (const float*)d_in[14];
  const float* gru_b_ih  = (const float*)d_in[15];
  const float* gru_b_hh  = (const float*)d_in[16];
  const float* lstm_w_ih = (const float*)d_in[17];
  const float* lstm_w_hh = (const float*)d_in[18];
  const float* lstm_b_ih = (const float*)d_in[19];
  const float* lstm_b_hh = (const float*)d_in[20];
  const float* lin1_w = (const float*)d_in[21];
  const float* lin1_b = (const float*)d_in[22];
  const float* lin2_w = (const float*)d_in[23];
  const float* lin2_b = (const float*)d_in[24];
  (void)in_sizes; (void)n_in; (void)out_size;

  const int* srcA = ei;
  const int* tgtA = ei + N_EDGES;

  // ---- fixed workspace layout (~10 MB) ----
  char* p = (char*)d_ws;
  size_t off = 0;
  auto take = [&](size_t bytes)->char*{ char* q = p + off; off = alignup(off + bytes); return q; };
  _Float16* Bpack = (_Float16*)take((size_t)(HIDW*DD/32)*4*64*8*2);  // 1.05 MB
  float* sbuf    = (float*)take((size_t)N_NODES*DD*4);
  float* aggsum  = (float*)take((size_t)N_NODES*DD*4);
  float* Ssum    = (float*)take((size_t)N_NODES*DD*4);
  float* WihT    = (float*)take(12288*4);
  float* WhhT    = (float*)take(12288*4);
  float* IhT     = (float*)take(32768*4);
  float* HhT     = (float*)take(16384*4);
  float* deg     = (float*)take(N_NODES*4);
  int*   cnt     = (int*)  take(N_NODES*4);
  int*   offs    = (int*)  take((N_NODES+1)*4);
  int*   cursor  = (int*)  take(N_NODES*4);
  int*   sorted  = (int*)  take(N_EDGES*4);
  int*   goff    = (int*)  take(65*4);
  float* qstar   = (float*)take((size_t)N_GRAPH*2*DD*4);
  size_t fixed_bytes = off;

  // ---- adaptive P-chunk selection (fp16) ----
  int CH = 4;
  const int cands[6] = {128, 64, 32, 16, 8, 4};
  for (int ci = 0; ci < 6; ++ci){
    size_t need = fixed_bytes + (size_t)N_NODES * cands[ci] * 64 * 2;
    if (need <= ws_size){ CH = cands[ci]; break; }
  }
  _Float16* Pbuf = (_Float16*)take((size_t)N_NODES*CH*64*2);

  hipMemsetAsync(cnt, 0, N_NODES*4, stream);

  k_prep_bpack<<<(HIDW*DD/32)*4*64*8/256, 256, 0, stream>>>(h2_w, Bpack);
  k_prep_wT<<<(12288*2+32768+16384)/256, 256, 0, stream>>>(gru_w_ih, gru_w_hh, lstm_w_ih, lstm_w_hh,
                                                           WihT, WhhT, IhT, HhT);
  k_count<<<(N_EDGES+255)/256, 256, 0, stream>>>(tgtA, cnt);
  k_scan<<<1, 1024, 0, stream>>>(cnt, offs, cursor, deg);
  k_sortE<<<(N_EDGES+255)/256, 256, 0, stream>>>(tgtA, cursor, sorted);
  k_graphoff<<<1, 128, 0, stream>>>(batch, goff);
  k_lin0<<<N_NODES/4, 256, 0, stream>>>(x, lin0_w, lin0_b, sbuf);

  auto launch_agg = [&](int c0, bool writeS){
    dim3 g(N_NODES);
    if (writeS){
      switch (CH){
        case 128: k_aggpre_t<128,true><<<g,256,0,stream>>>(sbuf,ea,h1_w,h1_b,offs,sorted,srcA,c0,Pbuf,Ssum); break;
        case  64: k_aggpre_t< 64,true><<<g,256,0,stream>>>(sbuf,ea,h1_w,h1_b,offs,sorted,srcA,c0,Pbuf,Ssum); break;
        case  32: k_aggpre_t< 32,true><<<g,256,0,stream>>>(sbuf,ea,h1_w,h1_b,offs,sorted,srcA,c0,Pbuf,Ssum); break;
        case  16: k_aggpre_t< 16,true><<<g,256,0,stream>>>(sbuf,ea,h1_w,h1_b,offs,sorted,srcA,c0,Pbuf,Ssum); break;
        case   8: k_aggpre_t<  8,true><<<g,256,0,stream>>>(sbuf,ea,h1_w,h1_b,offs,sorted,srcA,c0,Pbuf,Ssum); break;
        default : k_aggpre_t<  4,true><<<g,256,0,stream>>>(sbuf,ea,h1_w,h1_b,offs,sorted,srcA,c0,Pbuf,Ssum); break;
      }
    } else {
      switch (CH){
        case 128: k_aggpre_t<128,false><<<g,256,0,stream>>>(sbuf,ea,h1_w,h1_b,offs,sorted,srcA,c0,Pbuf,Ssum); break;
        case  64: k_aggpre_t< 64,false><<<g,256,0,stream>>>(sbuf,ea,h1_w,h1_b,offs,sorted,srcA,c0,Pbuf,Ssum); break;
        case  32: k_aggpre_t< 32,false><<<g,256,0,stream>>>(sbuf,ea,h1_w,h1_b,offs,sorted,srcA,c0,Pbuf,Ssum); break;
        case  16: k_aggpre_t< 16,false><<<g,256,0,stream>>>(sbuf,ea,h1_w,h1_b,offs,sorted,srcA,c0,Pbuf,Ssum); break;
        case   8: k_aggpre_t<  8,false><<<g,256,0,stream>>>(sbuf,ea,h1_w,h1_b,offs,sorted,srcA,c0,Pbuf,Ssum); break;
        default : k_aggpre_t<  4,false><<<g,256,0,stream>>>(sbuf,ea,h1_w,h1_b,offs,sorted,srcA,c0,Pbuf,Ssum); break;
      }
    }
  };

  const int ngB = (N_NODES + 31) / 32;
  for (int it = 0; it < 3; ++it){
    int nch = HIDW / CH;
    for (int c = 0; c < nch; ++c){
      int c0 = c*CH;
      launch_agg(c0, c == 0);
      k_gemm_mfma<<<ngB, 128, 0, stream>>>(Pbuf, Bpack + (size_t)(c0*2)*(4*64*8),
                                           aggsum, CH*64, c == 0);
    }
    k_node_update<<<N_NODES/4, 256, 0, stream>>>(aggsum, Ssum, h2_b, deg, sbuf, conv_root, conv_bias,
                                                 WihT, WhhT, gru_b_ih, gru_b_hh);
  }

  k_set2set<<<N_GRAPH, 256, 0, stream>>>(sbuf, goff, IhT, HhT, lstm_b_ih, lstm_b_hh, qstar);
  k_final<<<1, 256, 0, stream>>>(qstar, lin1_w, lin1_b, lin2_w, lin2_b, (float*)d_out);
}

// Round 4
// 936.884 us; speedup vs baseline: 1.6784x; 1.1261x over previous
//
#include <hip/hip_runtime.h>
#include <math.h>

#define N_NODES 10000
#define N_EDGES 80000
#define N_GRAPH 64
#define DD 64
#define HIDW 128
#define F_IN 14
#define EAD 4
#define KS2 4   // K-split partial slots in the MFMA GEMM

typedef _Float16 f16x8 __attribute__((ext_vector_type(8)));
typedef float f32x4 __attribute__((ext_vector_type(4)));

__device__ __forceinline__ float sigmoidf_(float x){ return 1.0f/(1.0f+expf(-x)); }

// ---------- prep kernels ----------

// Pack Hext (h2_w rearranged) into fp16 MFMA B-fragment order:
// Bp[((st*4+cg)*64+lane)*8+j] = h2w[h, i*64+o], k=st*32+(lane>>4)*8+j, o=cg*16+(lane&15), h=k>>6, i=k&63
__global__ void k_prep_bpack(const float* __restrict__ h2w, _Float16* __restrict__ Bp){
  int idx = blockIdx.x*256 + threadIdx.x;
  if (idx >= (HIDW*DD/32)*4*64*8) return;
  int j = idx & 7, l = (idx >> 3) & 63, cg = (idx >> 9) & 3, st = idx >> 11;
  int k = st*32 + ((l >> 4) << 3) + j;
  int o = cg*16 + (l & 15);
  int h = k >> 6, i = k & 63;
  Bp[idx] = (_Float16)h2w[(size_t)h*4096 + i*64 + o];
}

// transpose GRU / LSTM weight matrices to k-major for coalesced reads
__global__ void k_prep_wT(const float* __restrict__ gih, const float* __restrict__ ghh,
                          const float* __restrict__ lih, const float* __restrict__ lhh,
                          float* __restrict__ WihT, float* __restrict__ WhhT,
                          float* __restrict__ IhT,  float* __restrict__ HhT){
  int idx = blockIdx.x*256 + threadIdx.x;
  if (idx < 12288){ int k=idx/192, j=idx%192; WihT[idx]=gih[j*64+k]; return; }
  idx -= 12288;
  if (idx < 12288){ int k=idx/192, j=idx%192; WhhT[idx]=ghh[j*64+k]; return; }
  idx -= 12288;
  if (idx < 32768){ int k=idx>>8, j=idx&255; IhT[idx]=lih[j*128+k]; return; }
  idx -= 32768;
  if (idx < 16384){ int k=idx>>8, j=idx&255; HhT[idx]=lhh[j*64+k]; return; }
}

// ---------- CSR build (sort edges by target) ----------

__global__ void k_count(const int* __restrict__ tgt, int* __restrict__ cnt){
  int e = blockIdx.x*256 + threadIdx.x;
  if (e < N_EDGES) atomicAdd(&cnt[tgt[e]], 1);
}

__global__ __launch_bounds__(1024) void k_scan(const int* __restrict__ cnt, int* __restrict__ offs,
                                               int* __restrict__ cursor, float* __restrict__ deg){
  __shared__ int sc[1024];
  int t = threadIdx.x;
  int base = t*10;
  int loc[10]; int tot = 0;
  #pragma unroll
  for (int j=0;j<10;++j){
    int i = base+j;
    int c = (i < N_NODES) ? cnt[i] : 0;
    loc[j] = tot; tot += c;
  }
  sc[t] = tot; __syncthreads();
  for (int st=1; st<1024; st<<=1){
    int v = (t>=st) ? sc[t-st] : 0;
    __syncthreads();
    sc[t] += v;
    __syncthreads();
  }
  int ex = sc[t] - tot;
  #pragma unroll
  for (int j=0;j<10;++j){
    int i = base+j;
    if (i < N_NODES){
      int o = ex + loc[j];
      offs[i] = o; cursor[i] = o;
      int c = cnt[i];
      deg[i] = (float)(c > 0 ? c : 1);
    }
  }
  if (t == 1023) offs[N_NODES] = sc[1023];
}

__global__ void k_sortE(const int* __restrict__ tgt, int* __restrict__ cursor, int* __restrict__ sorted){
  int e = blockIdx.x*256 + threadIdx.x;
  if (e < N_EDGES){ int p = atomicAdd(&cursor[tgt[e]], 1); sorted[p] = e; }
}

__global__ void k_graphoff(const int* __restrict__ batch, int* __restrict__ goff){
  int g = threadIdx.x;
  if (g > N_GRAPH) return;
  int lo = 0, hi = N_NODES;
  while (lo < hi){ int mid = (lo+hi)>>1; if (batch[mid] < g) lo = mid+1; else hi = mid; }
  goff[g] = lo;
}

// ---------- input layer ----------

__global__ __launch_bounds__(256) void k_lin0(const float* __restrict__ x, const float* __restrict__ w,
                                              const float* __restrict__ b, float* __restrict__ s){
  int tid = threadIdx.x;
  int g = tid >> 6, o = tid & 63;
  int n = blockIdx.x*4 + g;
  __shared__ float xL[4][F_IN];
  if (tid < 4*F_IN){
    int gg = tid / F_IN, k = tid % F_IN;
    int nn = blockIdx.x*4 + gg;
    xL[gg][k] = (nn < N_NODES) ? x[nn*F_IN + k] : 0.f;
  }
  __syncthreads();
  if (n >= N_NODES) return;
  float acc = b[o];
  #pragma unroll
  for (int k=0;k<F_IN;++k) acc += xL[g][k]*w[k*64+o];
  s[n*64+o] = fmaxf(acc, 0.f);
}

// ---------- per-iteration: P build (fp16 out) + MFMA GEMM ----------

template<int CH, bool WRITE_S>
__global__ __launch_bounds__(256) void k_aggpre_t(
    const float* __restrict__ s, const float* __restrict__ ea,
    const float* __restrict__ h1_w, const float* __restrict__ h1_b,
    const int* __restrict__ offs, const int* __restrict__ sorted,
    const int* __restrict__ srcA, int c0,
    _Float16* __restrict__ P, float* __restrict__ Ssum){
  constexpr int RH = CH/4;
  int t = blockIdx.x;
  int tid = threadIdx.x;
  int i = tid & 63, hb = tid >> 6;
  __shared__ float sL[4][64];
  __shared__ float hidL[4][CH];
  __shared__ int eIdx[4], sIdx[4];
  float acc[RH];
  #pragma unroll
  for (int r=0;r<RH;++r) acc[r]=0.f;
  float sacc = 0.f;
  int e0 = offs[t], e1 = offs[t+1];
  for (int base = e0; base < e1; base += 4){
    int ecnt = min(4, e1 - base);
    __syncthreads();
    if (tid < ecnt){
      int e = sorted[base + tid];
      eIdx[tid] = e;
      sIdx[tid] = srcA[e];
    }
    __syncthreads();
    if (hb < ecnt) sL[hb][i] = s[(size_t)sIdx[hb]*64 + i];
    for (int a = tid; a < 4*CH; a += 256){
      int j = a / CH, hh = a % CH;
      if (j < ecnt){
        int e = eIdx[j];
        int h = c0 + hh;
        float v = h1_b[h];
        #pragma unroll
        for (int k=0;k<EAD;++k) v += ea[e*EAD+k]*h1_w[k*HIDW + h];
        hidL[j][hh] = fmaxf(v, 0.f);
      }
    }
    __syncthreads();
    for (int j=0;j<ecnt;++j){
      float sv = sL[j][i];
      #pragma unroll
      for (int r=0;r<RH;++r) acc[r] += hidL[j][hb*RH + r]*sv;
      if (WRITE_S && hb==0) sacc += sv;
    }
  }
  _Float16* row = P + (size_t)t*(CH*64);
  #pragma unroll
  for (int r=0;r<RH;++r) row[(hb*RH + r)*64 + i] = (_Float16)acc[r];
  if (WRITE_S && hb==0) Ssum[(size_t)t*64 + i] = sacc;
}

// Cpart[ks][10000][64] (+)= A[10000,K] @ B[K,64] via mfma_f32_16x16x32_f16.
// 4 waves/block: wave = col-group cg (16 cols). blockIdx.y = K-split slot.
// 10000 = 625*16 rows exactly. first: chunk 0 writes, later chunks accumulate.
__global__ __launch_bounds__(256) void k_gemm_mfma(const _Float16* __restrict__ A,
    const _Float16* __restrict__ Bp, float* __restrict__ Cpart, int K, int first){
  int cg = threadIdx.x >> 6, lane = threadIdx.x & 63;
  int rowA = blockIdx.x*16 + (lane & 15);
  int kb = lane >> 4;
  const _Float16* arow = A + (size_t)rowA*K + kb*8;
  const f16x8* bp = (const f16x8*)Bp;
  f32x4 acc = 0.f;
  int nst = K >> 7;              // K / (32*KS2)
  int st0 = blockIdx.y * nst;
  #pragma unroll 4
  for (int s = 0; s < nst; ++s){
    int st = st0 + s;
    f16x8 af = *(const f16x8*)(arow + (size_t)st*32);
    f16x8 bf = bp[(size_t)(st*4 + cg)*64 + lane];
    acc = __builtin_amdgcn_mfma_f32_16x16x32_f16(af, bf, acc, 0, 0, 0);
  }
  int crow0 = blockIdx.x*16 + kb*4;
  int ccol = cg*16 + (lane & 15);
  float* base = Cpart + (size_t)blockIdx.y*(N_NODES*64);
  #pragma unroll
  for (int r=0;r<4;++r){
    float* cp = base + (size_t)(crow0 + r)*64 + ccol;
    if (first) *cp = acc[r];
    else       *cp += acc[r];
  }
}

// fused: KS2-slot reduce, mean-deg, bias term (Ssum@h2b), conv-root, relu, GRU cell
__global__ __launch_bounds__(256) void k_node_update(const float* __restrict__ Cpart,
    const float* __restrict__ Ssum, const float* __restrict__ h2b,
    const float* __restrict__ deg, float* __restrict__ s,
    const float* __restrict__ conv_root, const float* __restrict__ conv_bias,
    const float* __restrict__ WihT, const float* __restrict__ WhhT,
    const float* __restrict__ bih, const float* __restrict__ bhh){
  int tid = threadIdx.x;
  int g = tid >> 6, o = tid & 63;
  int n = blockIdx.x*4 + g;
  __shared__ float hS[4][DD];
  __shared__ float mS[4][DD];
  __shared__ float ssS[4][DD];
  bool valid = n < N_NODES;
  float hold = valid ? s[(size_t)n*DD + o] : 0.f;
  hS[g][o] = hold;
  ssS[g][o] = valid ? Ssum[(size_t)n*DD + o] : 0.f;
  __syncthreads();
  float a = 0.f;
  if (valid){
    #pragma unroll
    for (int ks=0; ks<KS2; ++ks) a += Cpart[(size_t)ks*(N_NODES*64) + (size_t)n*64 + o];
  }
  #pragma unroll 8
  for (int k=0;k<DD;++k) a += ssS[g][k]*h2b[k*64+o];
  float dinv = valid ? 1.0f/deg[n] : 0.f;
  float acc = a*dinv + conv_bias[o];
  #pragma unroll 8
  for (int k=0;k<DD;++k) acc += hS[g][k]*conv_root[k*64+o];
  float m = fmaxf(acc, 0.f);
  mS[g][o] = m;
  __syncthreads();
  float gi0 = bih[o], gi1 = bih[64+o], gi2 = bih[128+o];
  float gh0 = bhh[o], gh1 = bhh[64+o], gh2 = bhh[128+o];
  for (int k=0;k<DD;++k){
    float mk = mS[g][k], hk = hS[g][k];
    gi0 += mk*WihT[k*192 + o];      gh0 += hk*WhhT[k*192 + o];
    gi1 += mk*WihT[k*192 + 64 + o]; gh1 += hk*WhhT[k*192 + 64 + o];
    gi2 += mk*WihT[k*192 + 128+ o]; gh2 += hk*WhhT[k*192 + 128+ o];
  }
  float r = sigmoidf_(gi0+gh0);
  float z = sigmoidf_(gi1+gh1);
  float nn = tanhf(gi2 + r*gh2);
  float hnew = (1.f - z)*nn + z*hold;
  if (valid) s[(size_t)n*DD + o] = hnew;
}

// ---------- Set2Set: all 3 steps fused, one block per graph ----------

__global__ __launch_bounds__(256) void k_set2set(const float* __restrict__ sND,
    const int* __restrict__ goff,
    const float* __restrict__ IhT, const float* __restrict__ HhT,
    const float* __restrict__ bih, const float* __restrict__ bhh,
    float* __restrict__ qstarOut){
  int g = blockIdx.x;
  int tid = threadIdx.x;
  int lane = tid & 63, w = tid >> 6;
  __shared__ float qL[2*DD];
  __shared__ float hL[DD];
  __shared__ float cL[DD];
  __shared__ float gate[256];
  __shared__ float red[4];
  __shared__ float red2[4][DD];
  if (tid < 2*DD) qL[tid] = 0.f;
  if (tid < DD){ hL[tid] = 0.f; cL[tid] = 0.f; }
  __syncthreads();
  int n0 = goff[g], n1 = goff[g+1];
  for (int st = 0; st < 3; ++st){
    float acc = bih[tid] + bhh[tid];
    #pragma unroll 8
    for (int k=0;k<2*DD;++k) acc += qL[k]*IhT[k*256 + tid];
    #pragma unroll 8
    for (int k=0;k<DD;++k)   acc += hL[k]*HhT[k*256 + tid];
    gate[tid] = acc;
    __syncthreads();
    if (tid < DD){
      float i = sigmoidf_(gate[tid]);
      float f = sigmoidf_(gate[64+tid]);
      float gg = tanhf(gate[128+tid]);
      float o = sigmoidf_(gate[192+tid]);
      float c = f*cL[tid] + i*gg;
      float h = o*tanhf(c);
      cL[tid] = c; hL[tid] = h;
    }
    __syncthreads();
    float wmax = -INFINITY;
    for (int n = n0 + w; n < n1; n += 4){
      float p = sND[(size_t)n*DD + lane] * hL[lane];
      #pragma unroll
      for (int s2=32; s2>0; s2>>=1) p += __shfl_xor(p, s2, 64);
      wmax = fmaxf(wmax, p);
    }
    if (lane == 0) red[w] = wmax;
    __syncthreads();
    float m = fmaxf(fmaxf(red[0], red[1]), fmaxf(red[2], red[3]));
    __syncthreads();
    float wsum = 0.f, racc = 0.f;
    for (int n = n0 + w; n < n1; n += 4){
      float outv = sND[(size_t)n*DD + lane];
      float p = outv * hL[lane];
      #pragma unroll
      for (int s2=32; s2>0; s2>>=1) p += __shfl_xor(p, s2, 64);
      float ex = expf(p - m);
      wsum += ex;
      racc += ex * outv;
    }
    if (lane == 0) red[w] = wsum;
    red2[w][lane] = racc;
    __syncthreads();
    if (tid < DD){
      float stot = red[0]+red[1]+red[2]+red[3];
      float rsum = red2[0][tid]+red2[1][tid]+red2[2][tid]+red2[3][tid];
      float r = (stot > 0.f) ? rsum/stot : 0.f;
      qL[tid] = hL[tid];
      qL[DD + tid] = r;
    }
    __syncthreads();
  }
  if (tid < 2*DD) qstarOut[g*2*DD + tid] = qL[tid];
}

__global__ __launch_bounds__(256) void k_final(const float* __restrict__ qstar,
    const float* __restrict__ lin1_w, const float* __restrict__ lin1_b,
    const float* __restrict__ lin2_w, const float* __restrict__ lin2_b,
    float* __restrict__ out){
  __shared__ float red[256];
  int tid = threadIdx.x;
  int g = tid >> 2, part = tid & 3;
  float acc = 0.f;
  for (int d = part*16; d < part*16+16; ++d){
    float z = lin1_b[d];
    #pragma unroll 8
    for (int k=0;k<2*DD;++k) z += qstar[g*2*DD+k]*lin1_w[k*64+d];
    z = fmaxf(z, 0.f);
    acc += z * lin2_w[d];
  }
  red[tid] = acc;
  __syncthreads();
  if (part == 0) out[g] = red[tid]+red[tid+1]+red[tid+2]+red[tid+3] + lin2_b[0];
}

// ---------- launch ----------

static inline size_t alignup(size_t x){ return (x + 255) & ~(size_t)255; }

extern "C" void kernel_launch(void* const* d_in, const int* in_sizes, int n_in,
                              void* d_out, int out_size, void* d_ws, size_t ws_size,
                              hipStream_t stream){
  const float* x      = (const float*)d_in[0];
  const int*   ei     = (const int*)  d_in[1];
  const float* ea     = (const float*)d_in[2];
  const int*   batch  = (const int*)  d_in[3];
  const float* lin0_w = (const float*)d_in[5];
  const float* lin0_b = (const float*)d_in[6];
  const float* h1_w   = (const float*)d_in[7];
  const float* h1_b   = (const float*)d_in[8];
  const float* h2_w   = (const float*)d_in[9];
  const float* h2_b   = (const float*)d_in[10];
  const float* conv_root = (const float*)d_in[11];
  const float* conv_bias = (const float*)d_in[12];
  const float* gru_w_ih  = (const float*)d_in[13];
  const float* gru_w_hh  = (const float*)d_in[14];
  const float* gru_b_ih  = (const float*)d_in[15];
  const float* gru_b_hh  = (const float*)d_in[16];
  const float* lstm_w_ih = (const float*)d_in[17];
  const float* lstm_w_hh = (const float*)d_in[18];
  const float* lstm_b_ih = (const float*)d_in[19];
  const float* lstm_b_hh = (const float*)d_in[20];
  const float* lin1_w = (const float*)d_in[21];
  const float* lin1_b = (const float*)d_in[22];
  const float* lin2_w = (const float*)d_in[23];
  const float* lin2_b = (const float*)d_in[24];
  (void)in_sizes; (void)n_in; (void)out_size;

  const int* srcA = ei;
  const int* tgtA = ei + N_EDGES;

  // ---- fixed workspace layout (~20 MB) ----
  char* p = (char*)d_ws;
  size_t off = 0;
  auto take = [&](size_t bytes)->char*{ char* q = p + off; off = alignup(off + bytes); return q; };
  _Float16* Bpack = (_Float16*)take((size_t)(HIDW*DD/32)*4*64*8*2);  // 1.05 MB
  float* sbuf    = (float*)take((size_t)N_NODES*DD*4);
  float* Cpart   = (float*)take((size_t)KS2*N_NODES*DD*4);           // 10.24 MB
  float* Ssum    = (float*)take((size_t)N_NODES*DD*4);
  float* WihT    = (float*)take(12288*4);
  float* WhhT    = (float*)take(12288*4);
  float* IhT     = (float*)take(32768*4);
  float* HhT     = (float*)take(16384*4);
  float* deg     = (float*)take(N_NODES*4);
  int*   cnt     = (int*)  take(N_NODES*4);
  int*   offs    = (int*)  take((N_NODES+1)*4);
  int*   cursor  = (int*)  take(N_NODES*4);
  int*   sorted  = (int*)  take(N_EDGES*4);
  int*   goff    = (int*)  take(65*4);
  float* qstar   = (float*)take((size_t)N_GRAPH*2*DD*4);
  size_t fixed_bytes = off;

  // ---- adaptive P-chunk selection (fp16) ----
  int CH = 4;
  const int cands[6] = {128, 64, 32, 16, 8, 4};
  for (int ci = 0; ci < 6; ++ci){
    size_t need = fixed_bytes + (size_t)N_NODES * cands[ci] * 64 * 2;
    if (need <= ws_size){ CH = cands[ci]; break; }
  }
  _Float16* Pbuf = (_Float16*)take((size_t)N_NODES*CH*64*2);

  hipMemsetAsync(cnt, 0, N_NODES*4, stream);

  k_prep_bpack<<<(HIDW*DD/32)*4*64*8/256, 256, 0, stream>>>(h2_w, Bpack);
  k_prep_wT<<<(12288*2+32768+16384)/256, 256, 0, stream>>>(gru_w_ih, gru_w_hh, lstm_w_ih, lstm_w_hh,
                                                           WihT, WhhT, IhT, HhT);
  k_count<<<(N_EDGES+255)/256, 256, 0, stream>>>(tgtA, cnt);
  k_scan<<<1, 1024, 0, stream>>>(cnt, offs, cursor, deg);
  k_sortE<<<(N_EDGES+255)/256, 256, 0, stream>>>(tgtA, cursor, sorted);
  k_graphoff<<<1, 128, 0, stream>>>(batch, goff);
  k_lin0<<<N_NODES/4, 256, 0, stream>>>(x, lin0_w, lin0_b, sbuf);

  auto launch_agg = [&](int c0, bool writeS){
    dim3 g(N_NODES);
    if (writeS){
      switch (CH){
        case 128: k_aggpre_t<128,true><<<g,256,0,stream>>>(sbuf,ea,h1_w,h1_b,offs,sorted,srcA,c0,Pbuf,Ssum); break;
        case  64: k_aggpre_t< 64,true><<<g,256,0,stream>>>(sbuf,ea,h1_w,h1_b,offs,sorted,srcA,c0,Pbuf,Ssum); break;
        case  32: k_aggpre_t< 32,true><<<g,256,0,stream>>>(sbuf,ea,h1_w,h1_b,offs,sorted,srcA,c0,Pbuf,Ssum); break;
        case  16: k_aggpre_t< 16,true><<<g,256,0,stream>>>(sbuf,ea,h1_w,h1_b,offs,sorted,srcA,c0,Pbuf,Ssum); break;
        case   8: k_aggpre_t<  8,true><<<g,256,0,stream>>>(sbuf,ea,h1_w,h1_b,offs,sorted,srcA,c0,Pbuf,Ssum); break;
        default : k_aggpre_t<  4,true><<<g,256,0,stream>>>(sbuf,ea,h1_w,h1_b,offs,sorted,srcA,c0,Pbuf,Ssum); break;
      }
    } else {
      switch (CH){
        case 128: k_aggpre_t<128,false><<<g,256,0,stream>>>(sbuf,ea,h1_w,h1_b,offs,sorted,srcA,c0,Pbuf,Ssum); break;
        case  64: k_aggpre_t< 64,false><<<g,256,0,stream>>>(sbuf,ea,h1_w,h1_b,offs,sorted,srcA,c0,Pbuf,Ssum); break;
        case  32: k_aggpre_t< 32,false><<<g,256,0,stream>>>(sbuf,ea,h1_w,h1_b,offs,sorted,srcA,c0,Pbuf,Ssum); break;
        case  16: k_aggpre_t< 16,false><<<g,256,0,stream>>>(sbuf,ea,h1_w,h1_b,offs,sorted,srcA,c0,Pbuf,Ssum); break;
        case   8: k_aggpre_t<  8,false><<<g,256,0,stream>>>(sbuf,ea,h1_w,h1_b,offs,sorted,srcA,c0,Pbuf,Ssum); break;
        default : k_aggpre_t<  4,false><<<g,256,0,stream>>>(sbuf,ea,h1_w,h1_b,offs,sorted,srcA,c0,Pbuf,Ssum); break;
      }
    }
  };

  for (int it = 0; it < 3; ++it){
    int nch = HIDW / CH;
    for (int c = 0; c < nch; ++c){
      int c0 = c*CH;
      launch_agg(c0, c == 0);
      k_gemm_mfma<<<dim3(N_NODES/16, KS2), 256, 0, stream>>>(Pbuf, Bpack + (size_t)(c0*2)*(4*64*8),
                                                             Cpart, CH*64, c == 0);
    }
    k_node_update<<<N_NODES/4, 256, 0, stream>>>(Cpart, Ssum, h2_b, deg, sbuf, conv_root, conv_bias,
                                                 WihT, WhhT, gru_b_ih, gru_b_hh);
  }

  k_set2set<<<N_GRAPH, 256, 0, stream>>>(sbuf, goff, IhT, HhT, lstm_b_ih, lstm_b_hh, qstar);
  k_final<<<1, 256, 0, stream>>>(qstar, lin1_w, lin1_b, lin2_w, lin2_b, (float*)d_out);
}

// Round 6
// 743.166 us; speedup vs baseline: 2.1159x; 1.2607x over previous
//
#include <hip/hip_runtime.h>
#include <math.h>

#define N_NODES 10000
#define N_EDGES 80000
#define N_GRAPH 64
#define DD 64
#define HIDW 128
#define F_IN 14
#define EAD 4
#define KSMAX 8   // max K-split partial slots (CH=128 -> 8 slots of 1024 halves)

typedef _Float16 f16x8 __attribute__((ext_vector_type(8)));
typedef float f32x4 __attribute__((ext_vector_type(4)));

__device__ __forceinline__ float sigmoidf_(float x){ return 1.0f/(1.0f+expf(-x)); }

// ---------- prep kernels ----------

// Pack Hext (h2_w rearranged) into fp16 MFMA B-fragment order:
// Bp[((st*4+cg)*64+lane)*8+j] = h2w[h, i*64+o], k=st*32+(lane>>4)*8+j, o=cg*16+(lane&15), h=k>>6, i=k&63
__global__ void k_prep_bpack(const float* __restrict__ h2w, _Float16* __restrict__ Bp){
  int idx = blockIdx.x*256 + threadIdx.x;
  if (idx >= (HIDW*DD/32)*4*64*8) return;
  int j = idx & 7, l = (idx >> 3) & 63, cg = (idx >> 9) & 3, st = idx >> 11;
  int k = st*32 + ((l >> 4) << 3) + j;
  int o = cg*16 + (l & 15);
  int h = k >> 6, i = k & 63;
  Bp[idx] = (_Float16)h2w[(size_t)h*4096 + i*64 + o];
}

// transpose GRU / LSTM weight matrices to k-major for coalesced reads
__global__ void k_prep_wT(const float* __restrict__ gih, const float* __restrict__ ghh,
                          const float* __restrict__ lih, const float* __restrict__ lhh,
                          float* __restrict__ WihT, float* __restrict__ WhhT,
                          float* __restrict__ IhT,  float* __restrict__ HhT){
  int idx = blockIdx.x*256 + threadIdx.x;
  if (idx < 12288){ int k=idx/192, j=idx%192; WihT[idx]=gih[j*64+k]; return; }
  idx -= 12288;
  if (idx < 12288){ int k=idx/192, j=idx%192; WhhT[idx]=ghh[j*64+k]; return; }
  idx -= 12288;
  if (idx < 32768){ int k=idx>>8, j=idx&255; IhT[idx]=lih[j*128+k]; return; }
  idx -= 32768;
  if (idx < 16384){ int k=idx>>8, j=idx&255; HhT[idx]=lhh[j*64+k]; return; }
}

// ---------- CSR build (sort edges by target) ----------

__global__ void k_count(const int* __restrict__ tgt, int* __restrict__ cnt){
  int e = blockIdx.x*256 + threadIdx.x;
  if (e < N_EDGES) atomicAdd(&cnt[tgt[e]], 1);
}

__global__ __launch_bounds__(1024) void k_scan(const int* __restrict__ cnt, int* __restrict__ offs,
                                               int* __restrict__ cursor, float* __restrict__ deg){
  __shared__ int sc[1024];
  int t = threadIdx.x;
  int base = t*10;
  int loc[10]; int tot = 0;
  #pragma unroll
  for (int j=0;j<10;++j){
    int i = base+j;
    int c = (i < N_NODES) ? cnt[i] : 0;
    loc[j] = tot; tot += c;
  }
  sc[t] = tot; __syncthreads();
  for (int st=1; st<1024; st<<=1){
    int v = (t>=st) ? sc[t-st] : 0;
    __syncthreads();
    sc[t] += v;
    __syncthreads();
  }
  int ex = sc[t] - tot;
  #pragma unroll
  for (int j=0;j<10;++j){
    int i = base+j;
    if (i < N_NODES){
      int o = ex + loc[j];
      offs[i] = o; cursor[i] = o;
      int c = cnt[i];
      deg[i] = (float)(c > 0 ? c : 1);
    }
  }
  if (t == 1023) offs[N_NODES] = sc[1023];
}

__global__ void k_sortE(const int* __restrict__ tgt, int* __restrict__ cursor, int* __restrict__ sorted){
  int e = blockIdx.x*256 + threadIdx.x;
  if (e < N_EDGES){ int p = atomicAdd(&cursor[tgt[e]], 1); sorted[p] = e; }
}

__global__ void k_graphoff(const int* __restrict__ batch, int* __restrict__ goff){
  int g = threadIdx.x;
  if (g > N_GRAPH) return;
  int lo = 0, hi = N_NODES;
  while (lo < hi){ int mid = (lo+hi)>>1; if (batch[mid] < g) lo = mid+1; else hi = mid; }
  goff[g] = lo;
}

// ---------- input layer ----------

__global__ __launch_bounds__(256) void k_lin0(const float* __restrict__ x, const float* __restrict__ w,
                                              const float* __restrict__ b, float* __restrict__ s){
  int tid = threadIdx.x;
  int g = tid >> 6, o = tid & 63;
  int n = blockIdx.x*4 + g;
  __shared__ float xL[4][F_IN];
  if (tid < 4*F_IN){
    int gg = tid / F_IN, k = tid % F_IN;
    int nn = blockIdx.x*4 + gg;
    xL[gg][k] = (nn < N_NODES) ? x[nn*F_IN + k] : 0.f;
  }
  __syncthreads();
  if (n >= N_NODES) return;
  float acc = b[o];
  #pragma unroll
  for (int k=0;k<F_IN;++k) acc += xL[g][k]*w[k*64+o];
  s[n*64+o] = fmaxf(acc, 0.f);
}

// ---------- per-iteration: P build (fp16 out) + MFMA GEMM ----------

template<int CH, bool WRITE_S>
__global__ __launch_bounds__(256) void k_aggpre_t(
    const float* __restrict__ s, const float* __restrict__ ea,
    const float* __restrict__ h1_w, const float* __restrict__ h1_b,
    const int* __restrict__ offs, const int* __restrict__ sorted,
    const int* __restrict__ srcA, int c0,
    _Float16* __restrict__ P, float* __restrict__ Ssum){
  constexpr int RH = CH/4;
  int t = blockIdx.x;
  int tid = threadIdx.x;
  int i = tid & 63, hb = tid >> 6;
  __shared__ float sL[4][64];
  __shared__ float hidL[4][CH];
  __shared__ int eIdx[4], sIdx[4];
  float acc[RH];
  #pragma unroll
  for (int r=0;r<RH;++r) acc[r]=0.f;
  float sacc = 0.f;
  int e0 = offs[t], e1 = offs[t+1];
  for (int base = e0; base < e1; base += 4){
    int ecnt = min(4, e1 - base);
    __syncthreads();
    if (tid < ecnt){
      int e = sorted[base + tid];
      eIdx[tid] = e;
      sIdx[tid] = srcA[e];
    }
    __syncthreads();
    if (hb < ecnt) sL[hb][i] = s[(size_t)sIdx[hb]*64 + i];
    for (int a = tid; a < 4*CH; a += 256){
      int j = a / CH, hh = a % CH;
      if (j < ecnt){
        int e = eIdx[j];
        int h = c0 + hh;
        float v = h1_b[h];
        #pragma unroll
        for (int k=0;k<EAD;++k) v += ea[e*EAD+k]*h1_w[k*HIDW + h];
        hidL[j][hh] = fmaxf(v, 0.f);
      }
    }
    __syncthreads();
    for (int j=0;j<ecnt;++j){
      float sv = sL[j][i];
      #pragma unroll
      for (int r=0;r<RH;++r) acc[r] += hidL[j][hb*RH + r]*sv;
      if (WRITE_S && hb==0) sacc += sv;
    }
  }
  _Float16* row = P + (size_t)t*(CH*64);
  #pragma unroll
  for (int r=0;r<RH;++r) row[(hb*RH + r)*64 + i] = (_Float16)acc[r];
  if (WRITE_S && hb==0) Ssum[(size_t)t*64 + i] = sacc;
}

// Cpart[y][10000][64] (+)= A[10000,K] @ B[K,64] via LDS-staged mfma_f32_16x16x32_f16.
// Block: 16 rows x 1024-half K-slot (y = blockIdx.y). 4 waves = 4 col-groups.
// A-tile staged coalesced into 32KB LDS with XOR swizzle (col ^= (row&7)<<4) applied
// on the global SOURCE address (write side) and on the ds_read address (read side).
__global__ __launch_bounds__(256) void k_gemm_lds(const _Float16* __restrict__ A,
    const _Float16* __restrict__ Bp, float* __restrict__ Cpart, int K, int first){
  __shared__ _Float16 tile[16*1024];
  int tid = threadIdx.x;
  int y = blockIdx.y;
  const size_t rowBytes = (size_t)K*2;
  {
    int sub = tid >> 7;          // row within pair
    int colb = (tid & 127) * 16; // byte col 0..2032, contiguous per row-half
    const char* Abase = (const char*)A + (size_t)(blockIdx.x*16)*rowBytes + (size_t)y*2048;
    #pragma unroll
    for (int i = 0; i < 8; ++i){
      int r = i*2 + sub;
      f16x8 v = *(const f16x8*)(Abase + (size_t)r*rowBytes + (size_t)(colb ^ ((r&7)<<4)));
      *(f16x8*)((char*)tile + r*2048 + colb) = v;
    }
  }
  __syncthreads();
  int cg = tid >> 6, lane = tid & 63;
  int row = lane & 15, kb = lane >> 4;
  const char* tbase = (const char*)tile + row*2048;
  int swz = (row & 7) << 4;
  f32x4 acc = 0.f;
  int fr0 = y*32*4;   // global B-fragment base: (y*32+st)*4
  #pragma unroll 8
  for (int st = 0; st < 32; ++st){
    f16x8 af = *(const f16x8*)(tbase + ((st*64 + kb*16) ^ swz));
    f16x8 bf = *(const f16x8*)(Bp + ((size_t)(fr0 + st*4 + cg)*64 + lane)*8);
    acc = __builtin_amdgcn_mfma_f32_16x16x32_f16(af, bf, acc, 0, 0, 0);
  }
  int crow0 = blockIdx.x*16 + kb*4;
  int ccol = cg*16 + (lane & 15);
  float* base = Cpart + (size_t)y*(N_NODES*64);
  #pragma unroll
  for (int r=0;r<4;++r){
    float* cp = base + (size_t)(crow0 + r)*64 + ccol;
    if (first) *cp = acc[r];
    else       *cp += acc[r];
  }
}

// fused: nslots-slot reduce, mean-deg, bias term (Ssum@h2b), conv-root, relu, GRU cell
__global__ __launch_bounds__(256) void k_node_update(const float* __restrict__ Cpart,
    const float* __restrict__ Ssum, const float* __restrict__ h2b,
    const float* __restrict__ deg, float* __restrict__ s,
    const float* __restrict__ conv_root, const float* __restrict__ conv_bias,
    const float* __restrict__ WihT, const float* __restrict__ WhhT,
    const float* __restrict__ bih, const float* __restrict__ bhh, int nslots){
  int tid = threadIdx.x;
  int g = tid >> 6, o = tid & 63;
  int n = blockIdx.x*4 + g;
  __shared__ float hS[4][DD];
  __shared__ float mS[4][DD];
  __shared__ float ssS[4][DD];
  bool valid = n < N_NODES;
  float hold = valid ? s[(size_t)n*DD + o] : 0.f;
  hS[g][o] = hold;
  ssS[g][o] = valid ? Ssum[(size_t)n*DD + o] : 0.f;
  __syncthreads();
  float a = 0.f;
  if (valid){
    for (int ks=0; ks<nslots; ++ks) a += Cpart[(size_t)ks*(N_NODES*64) + (size_t)n*64 + o];
  }
  #pragma unroll 8
  for (int k=0;k<DD;++k) a += ssS[g][k]*h2b[k*64+o];
  float dinv = valid ? 1.0f/deg[n] : 0.f;
  float acc = a*dinv + conv_bias[o];
  #pragma unroll 8
  for (int k=0;k<DD;++k) acc += hS[g][k]*conv_root[k*64+o];
  float m = fmaxf(acc, 0.f);
  mS[g][o] = m;
  __syncthreads();
  float gi0 = bih[o], gi1 = bih[64+o], gi2 = bih[128+o];
  float gh0 = bhh[o], gh1 = bhh[64+o], gh2 = bhh[128+o];
  for (int k=0;k<DD;++k){
    float mk = mS[g][k], hk = hS[g][k];
    gi0 += mk*WihT[k*192 + o];      gh0 += hk*WhhT[k*192 + o];
    gi1 += mk*WihT[k*192 + 64 + o]; gh1 += hk*WhhT[k*192 + 64 + o];
    gi2 += mk*WihT[k*192 + 128+ o]; gh2 += hk*WhhT[k*192 + 128+ o];
  }
  float r = sigmoidf_(gi0+gh0);
  float z = sigmoidf_(gi1+gh1);
  float nn = tanhf(gi2 + r*gh2);
  float hnew = (1.f - z)*nn + z*hold;
  if (valid) s[(size_t)n*DD + o] = hnew;
}

// ---------- Set2Set: all 3 steps fused, one block per graph ----------

__global__ __launch_bounds__(256) void k_set2set(const float* __restrict__ sND,
    const int* __restrict__ goff,
    const float* __restrict__ IhT, const float* __restrict__ HhT,
    const float* __restrict__ bih, const float* __restrict__ bhh,
    float* __restrict__ qstarOut){
  int g = blockIdx.x;
  int tid = threadIdx.x;
  int lane = tid & 63, w = tid >> 6;
  __shared__ float qL[2*DD];
  __shared__ float hL[DD];
  __shared__ float cL[DD];
  __shared__ float gate[256];
  __shared__ float red[4];
  __shared__ float red2[4][DD];
  if (tid < 2*DD) qL[tid] = 0.f;
  if (tid < DD){ hL[tid] = 0.f; cL[tid] = 0.f; }
  __syncthreads();
  int n0 = goff[g], n1 = goff[g+1];
  for (int st = 0; st < 3; ++st){
    float acc = bih[tid] + bhh[tid];
    #pragma unroll 8
    for (int k=0;k<2*DD;++k) acc += qL[k]*IhT[k*256 + tid];
    #pragma unroll 8
    for (int k=0;k<DD;++k)   acc += hL[k]*HhT[k*256 + tid];
    gate[tid] = acc;
    __syncthreads();
    if (tid < DD){
      float i = sigmoidf_(gate[tid]);
      float f = sigmoidf_(gate[64+tid]);
      float gg = tanhf(gate[128+tid]);
      float o = sigmoidf_(gate[192+tid]);
      float c = f*cL[tid] + i*gg;
      float h = o*tanhf(c);
      cL[tid] = c; hL[tid] = h;
    }
    __syncthreads();
    float wmax = -INFINITY;
    for (int n = n0 + w; n < n1; n += 4){
      float p = sND[(size_t)n*DD + lane] * hL[lane];
      #pragma unroll
      for (int s2=32; s2>0; s2>>=1) p += __shfl_xor(p, s2, 64);
      wmax = fmaxf(wmax, p);
    }
    if (lane == 0) red[w] = wmax;
    __syncthreads();
    float m = fmaxf(fmaxf(red[0], red[1]), fmaxf(red[2], red[3]));
    __syncthreads();
    float wsum = 0.f, racc = 0.f;
    for (int n = n0 + w; n < n1; n += 4){
      float outv = sND[(size_t)n*DD + lane];
      float p = outv * hL[lane];
      #pragma unroll
      for (int s2=32; s2>0; s2>>=1) p += __shfl_xor(p, s2, 64);
      float ex = expf(p - m);
      wsum += ex;
      racc += ex * outv;
    }
    if (lane == 0) red[w] = wsum;
    red2[w][lane] = racc;
    __syncthreads();
    if (tid < DD){
      float stot = red[0]+red[1]+red[2]+red[3];
      float rsum = red2[0][tid]+red2[1][tid]+red2[2][tid]+red2[3][tid];
      float r = (stot > 0.f) ? rsum/stot : 0.f;
      qL[tid] = hL[tid];
      qL[DD + tid] = r;
    }
    __syncthreads();
  }
  if (tid < 2*DD) qstarOut[g*2*DD + tid] = qL[tid];
}

__global__ __launch_bounds__(256) void k_final(const float* __restrict__ qstar,
    const float* __restrict__ lin1_w, const float* __restrict__ lin1_b,
    const float* __restrict__ lin2_w, const float* __restrict__ lin2_b,
    float* __restrict__ out){
  __shared__ float red[256];
  int tid = threadIdx.x;
  int g = tid >> 2, part = tid & 3;
  float acc = 0.f;
  for (int d = part*16; d < part*16+16; ++d){
    float z = lin1_b[d];
    #pragma unroll 8
    for (int k=0;k<2*DD;++k) z += qstar[g*2*DD+k]*lin1_w[k*64+d];
    z = fmaxf(z, 0.f);
    acc += z * lin2_w[d];
  }
  red[tid] = acc;
  __syncthreads();
  if (part == 0) out[g] = red[tid]+red[tid+1]+red[tid+2]+red[tid+3] + lin2_b[0];
}

// ---------- launch ----------

static inline size_t alignup(size_t x){ return (x + 255) & ~(size_t)255; }

extern "C" void kernel_launch(void* const* d_in, const int* in_sizes, int n_in,
                              void* d_out, int out_size, void* d_ws, size_t ws_size,
                              hipStream_t stream){
  const float* x      = (const float*)d_in[0];
  const int*   ei     = (const int*)  d_in[1];
  const float* ea     = (const float*)d_in[2];
  const int*   batch  = (const int*)  d_in[3];
  const float* lin0_w = (const float*)d_in[5];
  const float* lin0_b = (const float*)d_in[6];
  const float* h1_w   = (const float*)d_in[7];
  const float* h1_b   = (const float*)d_in[8];
  const float* h2_w   = (const float*)d_in[9];
  const float* h2_b   = (const float*)d_in[10];
  const float* conv_root = (const float*)d_in[11];
  const float* conv_bias = (const float*)d_in[12];
  const float* gru_w_ih  = (const float*)d_in[13];
  const float* gru_w_hh  = (const float*)d_in[14];
  const float* gru_b_ih  = (const float*)d_in[15];
  const float* gru_b_hh  = (const float*)d_in[16];
  const float* lstm_w_ih = (const float*)d_in[17];
  const float* lstm_w_hh = (const float*)d_in[18];
  const float* lstm_b_ih = (const float*)d_in[19];
  const float* lstm_b_hh = (const float*)d_in[20];
  const float* lin1_w = (const float*)d_in[21];
  const float* lin1_b = (const float*)d_in[22];
  const float* lin2_w = (const float*)d_in[23];
  const float* lin2_b = (const float*)d_in[24];
  (void)in_sizes; (void)n_in; (void)out_size;

  const int* srcA = ei;
  const int* tgtA = ei + N_EDGES;

  // ---- fixed workspace layout (~28 MB) ----
  char* p = (char*)d_ws;
  size_t off = 0;
  auto take = [&](size_t bytes)->char*{ char* q = p + off; off = alignup(off + bytes); return q; };
  _Float16* Bpack = (_Float16*)take((size_t)(HIDW*DD/32)*4*64*8*2);  // 1.05 MB
  float* sbuf    = (float*)take((size_t)N_NODES*DD*4);
  float* Cpart   = (float*)take((size_t)KSMAX*N_NODES*DD*4);         // 20.48 MB
  float* Ssum    = (float*)take((size_t)N_NODES*DD*4);
  float* WihT    = (float*)take(12288*4);
  float* WhhT    = (float*)take(12288*4);
  float* IhT     = (float*)take(32768*4);
  float* HhT     = (float*)take(16384*4);
  float* deg     = (float*)take(N_NODES*4);
  int*   cnt     = (int*)  take(N_NODES*4);
  int*   offs    = (int*)  take((N_NODES+1)*4);
  int*   cursor  = (int*)  take(N_NODES*4);
  int*   sorted  = (int*)  take(N_EDGES*4);
  int*   goff    = (int*)  take(65*4);
  float* qstar   = (float*)take((size_t)N_GRAPH*2*DD*4);
  size_t fixed_bytes = off;

  // ---- adaptive P-chunk selection (fp16); K per chunk = CH*64 >= 1024 ----
  int CH = 16;
  const int cands[4] = {128, 64, 32, 16};
  for (int ci = 0; ci < 4; ++ci){
    size_t need = fixed_bytes + (size_t)N_NODES * cands[ci] * 64 * 2;
    if (need <= ws_size){ CH = cands[ci]; break; }
  }
  _Float16* Pbuf = (_Float16*)take((size_t)N_NODES*CH*64*2);
  const int K = CH*64;
  const int nslots = K / 1024;   // Cpart slots per chunk (>=1)

  hipMemsetAsync(cnt, 0, N_NODES*4, stream);

  k_prep_bpack<<<(HIDW*DD/32)*4*64*8/256, 256, 0, stream>>>(h2_w, Bpack);
  k_prep_wT<<<(12288*2+32768+16384)/256, 256, 0, stream>>>(gru_w_ih, gru_w_hh, lstm_w_ih, lstm_w_hh,
                                                           WihT, WhhT, IhT, HhT);
  k_count<<<(N_EDGES+255)/256, 256, 0, stream>>>(tgtA, cnt);
  k_scan<<<1, 1024, 0, stream>>>(cnt, offs, cursor, deg);
  k_sortE<<<(N_EDGES+255)/256, 256, 0, stream>>>(tgtA, cursor, sorted);
  k_graphoff<<<1, 128, 0, stream>>>(batch, goff);
  k_lin0<<<N_NODES/4, 256, 0, stream>>>(x, lin0_w, lin0_b, sbuf);

  auto launch_agg = [&](int c0, bool writeS){
    dim3 g(N_NODES);
    if (writeS){
      switch (CH){
        case 128: k_aggpre_t<128,true><<<g,256,0,stream>>>(sbuf,ea,h1_w,h1_b,offs,sorted,srcA,c0,Pbuf,Ssum); break;
        case  64: k_aggpre_t< 64,true><<<g,256,0,stream>>>(sbuf,ea,h1_w,h1_b,offs,sorted,srcA,c0,Pbuf,Ssum); break;
        case  32: k_aggpre_t< 32,true><<<g,256,0,stream>>>(sbuf,ea,h1_w,h1_b,offs,sorted,srcA,c0,Pbuf,Ssum); break;
        default : k_aggpre_t< 16,true><<<g,256,0,stream>>>(sbuf,ea,h1_w,h1_b,offs,sorted,srcA,c0,Pbuf,Ssum); break;
      }
    } else {
      switch (CH){
        case 128: k_aggpre_t<128,false><<<g,256,0,stream>>>(sbuf,ea,h1_w,h1_b,offs,sorted,srcA,c0,Pbuf,Ssum); break;
        case  64: k_aggpre_t< 64,false><<<g,256,0,stream>>>(sbuf,ea,h1_w,h1_b,offs,sorted,srcA,c0,Pbuf,Ssum); break;
        case  32: k_aggpre_t< 32,false><<<g,256,0,stream>>>(sbuf,ea,h1_w,h1_b,offs,sorted,srcA,c0,Pbuf,Ssum); break;
        default : k_aggpre_t< 16,false><<<g,256,0,stream>>>(sbuf,ea,h1_w,h1_b,offs,sorted,srcA,c0,Pbuf,Ssum); break;
      }
    }
  };

  for (int it = 0; it < 3; ++it){
    int nch = HIDW / CH;
    for (int c = 0; c < nch; ++c){
      int c0 = c*CH;
      launch_agg(c0, c == 0);
      k_gemm_lds<<<dim3(N_NODES/16, nslots), 256, 0, stream>>>(Pbuf, Bpack + (size_t)(c0*2)*(4*64*8),
                                                               Cpart, K, c == 0);
    }
    k_node_update<<<N_NODES/4, 256, 0, stream>>>(Cpart, Ssum, h2_b, deg, sbuf, conv_root, conv_bias,
                                                 WihT, WhhT, gru_b_ih, gru_b_hh, nslots);
  }

  k_set2set<<<N_GRAPH, 256, 0, stream>>>(sbuf, goff, IhT, HhT, lstm_b_ih, lstm_b_hh, qstar);
  k_final<<<1, 256, 0, stream>>>(qstar, lin1_w, lin1_b, lin2_w, lin2_b, (float*)d_out);
}